// Round 6
// baseline (1064.643 us; speedup 1.0000x reference)
//
#include <hip/hip_runtime.h>
#include <hip/hip_bf16.h>
#include <math.h>

// Problem constants
constexpr int Bc = 2, Cc = 16, Dd = 64, Hh = 64, Ww = 64;
constexpr int HD = 128, WD = 128, Pp = 3;
constexpr int DHW = Dd * Hh * Ww;      // 262144
constexpr int HW = Hh * Ww;            // 4096
constexpr int XPH = 130, XPW = 130;    // padded xray
constexpr int XPS = XPH * XPW;         // 16900

struct Geom {
    double s0, s1, s2;      // source
    double c0ms0;           // center[0]-source[0]
    double tmin1, tmax1, tmin2, tmax2;
    double d1, d2;          // delta[1], delta[2]
};

__device__ __forceinline__ void xray_coord(const Geom g, int z, int x, int y,
                                           float& py, float& px) {
    double wgt = g.c0ms0 / ((double)z - g.s0);
    double X1 = wgt * ((double)x - g.s1) + g.s1;
    X1 = fmin(fmax(X1, g.tmin1), g.tmax1);
    double X2 = wgt * ((double)y - g.s2) + g.s2;
    X2 = fmin(fmax(X2, g.tmin2), g.tmax2);
    py = (float)((X1 - g.tmin1) / g.d1);
    px = (float)((X2 - g.tmin2) / g.d2);
}

// ---------------- pad Xray -> Xp (B,16,130,130) ----------------
__global__ __launch_bounds__(256) void k_pad(const float* __restrict__ X,
                                             float* __restrict__ Xp) {
    int i = blockIdx.x * 256 + threadIdx.x;
    if (i >= 32 * XPS) return;
    int bc = i / XPS;
    int r = i % XPS;
    int yy = r / XPW, xx = r % XPW;
    float v = 0.f;
    if (yy >= 1 && yy <= 128 && xx >= 1 && xx <= 128)
        v = X[bc * (HD * WD) + (yy - 1) * WD + (xx - 1)];
    Xp[i] = v;
}

// ---------------- weight transpose: w(COUT,CIN,27) -> wT(CIN,27,COUT) --------
__global__ __launch_bounds__(256) void k_wt(const float* __restrict__ w,
                                            float* __restrict__ wT,
                                            int COUT, int CIN) {
    int i = blockIdx.x * 256 + threadIdx.x;
    int n = COUT * CIN * 27;
    if (i >= n) return;
    int co = i / (CIN * 27);
    int r = i % (CIN * 27);
    int ci = r / 27, tap = r % 27;
    wT[(ci * 27 + tap) * COUT + co] = w[i];
}

// merged offset(6)+mask(3) weights -> wT9 (32,27,9), bias merge (9)
__global__ __launch_bounds__(256) void k_wt_merge(const float* __restrict__ pW,
                                                  const float* __restrict__ pb,
                                                  const float* __restrict__ mW,
                                                  const float* __restrict__ mb,
                                                  float* __restrict__ wT,
                                                  float* __restrict__ bm) {
    int i = blockIdx.x * 256 + threadIdx.x;
    if (i < 9 * 32 * 27) {
        int co = i / (32 * 27);
        int r = i % (32 * 27);
        int ci = r / 27, tap = r % 27;
        float v = (co < 6) ? pW[i] : mW[(co - 6) * 32 * 27 + r];
        wT[(ci * 27 + tap) * 9 + co] = v;
    }
    if (i < 9) bm[i] = (i < 6) ? pb[i] : mb[i - 6];
}

// ---------------- xi = bilerp_single(Xrc, Xray) -> (B,16,D,H,W) --------------
__global__ __launch_bounds__(256) void k_xi(const float* __restrict__ Xray,
                                            float* __restrict__ xi, Geom g) {
    int vox = blockIdx.x * 256 + threadIdx.x;  // 0..262143
    int z = vox >> 12, x = (vox >> 6) & 63, y = vox & 63;
    float py, px;
    xray_coord(g, z, x, y, py, px);
    float fy = floorf(py), fx = floorf(px);
    int y0 = (int)fminf(fmaxf(fy, 0.f), 127.f);
    int y1 = (int)fminf(fmaxf(fy + 1.f, 0.f), 127.f);
    int x0 = (int)fminf(fmaxf(fx, 0.f), 127.f);
    int x1 = (int)fminf(fmaxf(fx + 1.f, 0.f), 127.f);
    float y0f = (float)y0, y1f = (float)y1, x0f = (float)x0, x1f = (float)x1;
    float glt = (1.f + (y0f - py)) * (1.f + (x0f - px));
    float grb = (1.f - (y1f - py)) * (1.f - (x1f - px));
    float grt = (1.f + (y0f - py)) * (1.f - (x1f - px));
    float glb = (1.f - (y1f - py)) * (1.f + (x0f - px));
    int i00 = y0 * WD + x0, i11 = y1 * WD + x1, i01 = y0 * WD + x1, i10 = y1 * WD + x0;
    for (int bc = 0; bc < 32; ++bc) {
        const float* img = Xray + bc * (HD * WD);
        float v = glt * img[i00] + grb * img[i11] + grt * img[i01] + glb * img[i10];
        xi[bc * DHW + vox] = v;
    }
}

// ---------------- direct 3x3x3 conv, pad=1 -----------------------------------
// inA: first 16 channels, inB: second 16 (if CIN==32). wT: (CIN,27,COUT).
template <int CIN, int COUT, bool BN>
__global__ __launch_bounds__(256) void k_conv(const float* __restrict__ inA,
                                              const float* __restrict__ inB,
                                              const float* __restrict__ wT,
                                              const float* __restrict__ bias,
                                              const float* __restrict__ bng,
                                              const float* __restrict__ bnb,
                                              const float* __restrict__ bnm,
                                              const float* __restrict__ bnv,
                                              float* __restrict__ out) {
    __shared__ float lds[4 * 6 * 6 * 66];  // 9504 floats = 38KB
    int zt = blockIdx.x >> 4, xt = blockIdx.x & 15;
    int b = blockIdx.y;
    int tid = threadIdx.x;
    int y = tid & 63, xl = tid >> 6;  // xl: 0..3
    int z0 = zt * 4, x0 = xt * 4;
    float acc[4][COUT];
#pragma unroll
    for (int v = 0; v < 4; ++v)
#pragma unroll
        for (int co = 0; co < COUT; ++co) acc[v][co] = 0.f;

    constexpr int NCH = CIN / 4;
    for (int ch = 0; ch < NCH; ++ch) {
        __syncthreads();
        for (int idx = tid; idx < 4 * 6 * 6 * 66; idx += 256) {
            int yy = idx % 66;
            int t2 = idx / 66;
            int xx = t2 % 6;
            int t3 = t2 / 6;
            int zz = t3 % 6;
            int ci = t3 / 6;
            int gz = z0 - 1 + zz, gx = x0 - 1 + xx, gy = yy - 1;
            float v = 0.f;
            if ((unsigned)gz < 64u && (unsigned)gx < 64u && (unsigned)gy < 64u) {
                int cg = ch * 4 + ci;
                const float* src = (CIN == 16 || cg < 16)
                                       ? (inA + (size_t)(b * 16 + cg) * DHW)
                                       : (inB + (size_t)(b * 16 + (cg - 16)) * DHW);
                v = src[gz * HW + gx * 64 + gy];
            }
            lds[idx] = v;
        }
        __syncthreads();
        for (int ci = 0; ci < 4; ++ci) {
            int cg = ch * 4 + ci;
            const float* wrow = wT + (size_t)cg * 27 * COUT;
            for (int tap = 0; tap < 27; ++tap) {
                int dz = tap / 9;
                int dx = (tap / 3) % 3;
                int dy = tap % 3;
                float wv[COUT];
#pragma unroll
                for (int co = 0; co < COUT; ++co) wv[co] = wrow[tap * COUT + co];
                float iv[4];
#pragma unroll
                for (int v = 0; v < 4; ++v)
                    iv[v] = lds[((ci * 6 + (v + dz)) * 6 + (xl + dx)) * 66 + (y + dy)];
#pragma unroll
                for (int v = 0; v < 4; ++v)
#pragma unroll
                    for (int co = 0; co < COUT; ++co)
                        acc[v][co] = fmaf(iv[v], wv[co], acc[v][co]);
            }
        }
    }
#pragma unroll
    for (int co = 0; co < COUT; ++co) {
        float bi = bias[co];
        float bsc = 1.f, bsh = 0.f;
        if (BN) {
            float sc = bng[co] * rsqrtf(bnv[co] + 1e-5f);
            bsc = sc;
            bsh = bnb[co] - bnm[co] * sc;
        }
#pragma unroll
        for (int v = 0; v < 4; ++v) {
            float val = acc[v][co] + bi;
            if (BN) {
                val = val * bsc + bsh;
                val = (val >= 0.f) ? val : 0.2f * val;
            }
            out[(size_t)(b * COUT + co) * DHW + (z0 + v) * HW + (x0 + xl) * 64 + y] = val;
        }
    }
}

// ---------------- deform: softmax + p_coor + bilerp_multi sum ----------------
__global__ __launch_bounds__(256) void k_deform(const float* __restrict__ offm,
                                                const float* __restrict__ Xp,
                                                float* __restrict__ Xsum,
                                                float* __restrict__ pcoor, Geom g) {
    int idx = blockIdx.x * 256 + threadIdx.x;  // 0..524287
    int b = idx >> 18;
    int vox = idx & (DHW - 1);
    int z = vox >> 12, x = (vox >> 6) & 63, y = vox & 63;
    float bpy, bpx;
    xray_coord(g, z, x, y, bpy, bpx);
    const float* ob = offm + (size_t)b * 9 * DHW + vox;
    float off[6];
#pragma unroll
    for (int k = 0; k < 6; ++k) off[k] = ob[(size_t)k * DHW];
    float mv[3];
#pragma unroll
    for (int k = 0; k < 3; ++k) mv[k] = ob[(size_t)(6 + k) * DHW];
    float mx = fmaxf(mv[0], fmaxf(mv[1], mv[2]));
    float e0 = __expf(mv[0] - mx), e1 = __expf(mv[1] - mx), e2 = __expf(mv[2] - mx);
    float inv = 1.f / (e0 + e1 + e2);
    float m0 = e0 * inv, m1 = e1 * inv, m2 = e2 * inv;

    float pys[3], pxs[3];
#pragma unroll
    for (int p = 0; p < 3; ++p) {
        pys[p] = fminf(fmaxf(off[p] + bpy + 1.f, 0.f), 129.f);
        pxs[p] = fminf(fmaxf(off[3 + p] + bpx + 1.f, 0.f), 129.f);
    }
    float* pc = pcoor + (size_t)idx * 6;
    pc[0] = pys[0]; pc[1] = pys[1]; pc[2] = pys[2];
    pc[3] = pxs[0]; pc[4] = pxs[1]; pc[5] = pxs[2];

    float acc[16];
#pragma unroll
    for (int c = 0; c < 16; ++c) acc[c] = 0.f;
    const float* xpb = Xp + (size_t)b * 16 * XPS;
    float ms[3] = {m0, m1, m2};
#pragma unroll
    for (int p = 0; p < 3; ++p) {
        float py = pys[p], px = pxs[p];
        float fy = floorf(py), fx = floorf(px);
        int y0 = (int)fminf(fmaxf(fy, 0.f), 129.f);
        int y1 = (int)fminf(fmaxf(fy + 1.f, 0.f), 129.f);
        int x0 = (int)fminf(fmaxf(fx, 0.f), 129.f);
        int x1 = (int)fminf(fmaxf(fx + 1.f, 0.f), 129.f);
        float y0f = (float)y0, y1f = (float)y1, x0f = (float)x0, x1f = (float)x1;
        float glt = (1.f + (y0f - py)) * (1.f + (x0f - px));
        float grb = (1.f - (y1f - py)) * (1.f - (x1f - px));
        float grt = (1.f + (y0f - py)) * (1.f - (x1f - px));
        float glb = (1.f - (y1f - py)) * (1.f + (x0f - px));
        int i00 = y0 * XPW + x0, i11 = y1 * XPW + x1;
        int i01 = y0 * XPW + x1, i10 = y1 * XPW + x0;
        float mp = ms[p];
#pragma unroll
        for (int c = 0; c < 16; ++c) {
            const float* img = xpb + c * XPS;
            acc[c] += mp * (glt * img[i00] + grb * img[i11] +
                            grt * img[i01] + glb * img[i10]);
        }
    }
#pragma unroll
    for (int c = 0; c < 16; ++c)
        Xsum[(size_t)(b * 16 + c) * DHW + vox] = acc[c];
}

static void compute_geom(Geom& g) {
    const double sdr = 200.0, del = 2.0;
    double theta = M_PI, phi = 0.0, gam = M_PI / 2;
    double Rz[3][3] = {{cos(theta), -sin(theta), 0}, {sin(theta), cos(theta), 0}, {0, 0, 1}};
    double Ry[3][3] = {{cos(phi), 0, sin(phi)}, {0, 1, 0}, {-sin(phi), 0, cos(phi)}};
    double Rx[3][3] = {{1, 0, 0}, {0, cos(gam), -sin(gam)}, {0, sin(gam), cos(gam)}};
    double M[3][3], R[3][3];
    for (int i = 0; i < 3; i++)
        for (int j = 0; j < 3; j++) {
            double s = 0;
            for (int k = 0; k < 3; k++) s += Rz[i][k] * Ry[k][j];
            M[i][j] = s;
        }
    for (int i = 0; i < 3; i++)
        for (int j = 0; j < 3; j++) {
            double s = 0;
            for (int k = 0; k < 3; k++) s += M[i][k] * Rx[k][j];
            R[i][j] = sdr * s;
        }
    double trans[3] = {32.0, 32.0, 32.0};
    double src[3], ctr[3];
    for (int k = 0; k < 3; k++) {
        src[k] = R[k][0] + trans[k];
        ctr[k] = -R[k][0] + trans[k];
    }
    double Rn[3][3];
    for (int i = 0; i < 3; i++) {
        double n = sqrt(R[i][0] * R[i][0] + R[i][1] * R[i][1] + R[i][2] * R[i][2]);
        for (int j = 0; j < 3; j++) Rn[i][j] = R[i][j] / n;
    }
    double u[3], v[3];
    for (int k = 0; k < 3; k++) { u[k] = Rn[k][1]; v[k] = Rn[k][2]; }
    double tmin[3], tmax[3];
    for (int k = 0; k < 3; k++) {
        double a = 127.0 * fabs(u[k]) + 127.0 * fabs(v[k]);
        tmin[k] = ctr[k] - a;
        tmax[k] = ctr[k] + a;
    }
    double delta[3];
    for (int k = 0; k < 3; k++) delta[k] = del * u[k] + del * v[k];
    g.s0 = src[0]; g.s1 = src[1]; g.s2 = src[2];
    g.c0ms0 = ctr[0] - src[0];
    g.tmin1 = tmin[1]; g.tmax1 = tmax[1];
    g.tmin2 = tmin[2]; g.tmax2 = tmax[2];
    g.d1 = delta[1]; g.d2 = delta[2];
}

// workspace layout (float offsets)
constexpr size_t OFF_XI = 0;                            // 8388608
constexpr size_t OFF_XP = OFF_XI + (size_t)32 * DHW;    // 540800
constexpr size_t OFF_OFFM = OFF_XP + 32 * XPS;          // 9*B*DHW = 4718592
constexpr size_t OFF_XSUM = OFF_OFFM + (size_t)9 * Bc * DHW;
constexpr size_t OFF_H = OFF_XSUM + (size_t)32 * DHW;
constexpr size_t OFF_WT9 = OFF_H + (size_t)32 * DHW;    // 9*32*27 = 7776
constexpr size_t OFF_B9 = OFF_WT9 + 7776;               // 16
constexpr size_t OFF_WT1 = OFF_B9 + 16;                 // 16*32*27 = 13824
constexpr size_t OFF_WT2 = OFF_WT1 + 13824;             // 16*16*27 = 6912

extern "C" void kernel_launch(void* const* d_in, const int* in_sizes, int n_in,
                              void* d_out, int out_size, void* d_ws, size_t ws_size,
                              hipStream_t stream) {
    (void)in_sizes; (void)n_in; (void)out_size; (void)ws_size;
    const float* CT = (const float*)d_in[0];
    const float* Xray = (const float*)d_in[1];
    const float* pW = (const float*)d_in[2];
    const float* pb = (const float*)d_in[3];
    const float* mW = (const float*)d_in[4];
    const float* mb = (const float*)d_in[5];
    const float* w1 = (const float*)d_in[6];
    const float* b1 = (const float*)d_in[7];
    const float* w2 = (const float*)d_in[8];
    const float* b2 = (const float*)d_in[9];
    const float* bng = (const float*)d_in[10];
    const float* bnb = (const float*)d_in[11];
    const float* bnm = (const float*)d_in[12];
    const float* bnv = (const float*)d_in[13];

    float* ws = (float*)d_ws;
    float* xi = ws + OFF_XI;
    float* Xp = ws + OFF_XP;
    float* offm = ws + OFF_OFFM;
    float* Xsum = ws + OFF_XSUM;
    float* hbuf = ws + OFF_H;
    float* wT9 = ws + OFF_WT9;
    float* b9 = ws + OFF_B9;
    float* wT1 = ws + OFF_WT1;
    float* wT2 = ws + OFF_WT2;

    float* out0 = (float*)d_out;                 // (2,16,64,64,64)
    float* out1 = out0 + (size_t)32 * DHW;       // (2,64,64,64,6)

    Geom g;
    compute_geom(g);

    // weight prep
    k_wt_merge<<<31, 256, 0, stream>>>(pW, pb, mW, mb, wT9, b9);
    k_wt<<<54, 256, 0, stream>>>(w1, wT1, 16, 32);
    k_wt<<<27, 256, 0, stream>>>(w2, wT2, 16, 16);
    // pad xray
    k_pad<<<(32 * XPS + 255) / 256, 256, 0, stream>>>(Xray, Xp);
    // xi gather
    k_xi<<<DHW / 256, 256, 0, stream>>>(Xray, xi, g);
    // offset+mask conv (32 -> 9)
    k_conv<32, 9, false><<<dim3(256, Bc), 256, 0, stream>>>(
        CT, xi, wT9, b9, nullptr, nullptr, nullptr, nullptr, offm);
    // deform gather
    k_deform<<<(Bc * DHW) / 256, 256, 0, stream>>>(offm, Xp, Xsum, out1, g);
    // conv1 (32 -> 16) + BN + leaky
    k_conv<32, 16, true><<<dim3(256, Bc), 256, 0, stream>>>(
        CT, Xsum, wT1, b1, bng, bnb, bnm, bnv, hbuf);
    // conv2 (16 -> 16)
    k_conv<16, 16, false><<<dim3(256, Bc), 256, 0, stream>>>(
        hbuf, nullptr, wT2, b2, nullptr, nullptr, nullptr, nullptr, out0);
}

// Round 8
// 246.710 us; speedup vs baseline: 4.3154x; 4.3154x over previous
//
#include <hip/hip_runtime.h>
#include <hip/hip_bf16.h>
#include <math.h>

// Problem constants
constexpr int Dd = 64, Hh = 64, Ww = 64;
constexpr int HD = 128, WD = 128;
constexpr int DHW = Dd * Hh * Ww;   // 262144
constexpr int HW = Hh * Ww;         // 4096
constexpr int PD = 66;              // padded spatial dim (halo 1)
constexpr int PS3 = PD * PD * PD;   // 287496
constexpr int XT_S = 128 * 128;     // XrayT spatial
constexpr int XP_S = 130 * 130;     // padded xray spatial

using short8 = __attribute__((ext_vector_type(8))) short;
using f32x4  = __attribute__((ext_vector_type(4))) float;

struct Geom {
    double s0, s1, s2;
    double c0ms0;
    double tmin1, tmax1, tmin2, tmax2;
    double d1, d2;
};

__device__ __forceinline__ void xray_coord(const Geom g, int z, int x, int y,
                                           float& py, float& px) {
    double wgt = g.c0ms0 / ((double)z - g.s0);
    double X1 = wgt * ((double)x - g.s1) + g.s1;
    X1 = fmin(fmax(X1, g.tmin1), g.tmax1);
    double X2 = wgt * ((double)y - g.s2) + g.s2;
    X2 = fmin(fmax(X2, g.tmin2), g.tmax2);
    py = (float)((X1 - g.tmin1) / g.d1);
    px = (float)((X2 - g.tmin2) / g.d2);
}

__device__ __forceinline__ float bf2f(unsigned short u) {
    union { unsigned int i; float f; } v;
    v.i = ((unsigned int)u) << 16;
    return v.f;
}
__device__ __forceinline__ unsigned short f2bf(float f) {
    __hip_bfloat16 h = __float2bfloat16(f);
    return *reinterpret_cast<unsigned short*>(&h);
}

// ---------- weight prep: wB[s][lane][j] bf16 in MFMA B-frag order ------------
// B-frag element: w[cout = lane&15][k = s*32 + (lane>>4)*8 + j], k = tap*CIN+ci
template <int CIN, int NK>
__global__ __launch_bounds__(256) void k_wprep(const float* __restrict__ w6,
                                               const float* __restrict__ w3,
                                               unsigned short* __restrict__ wB) {
    int i = blockIdx.x * 256 + threadIdx.x;
    if (i >= NK * 64 * 8) return;
    int s = i >> 9, l = (i >> 3) & 63, j = i & 7;
    int n = l & 15, q = l >> 4;
    int k = s * 32 + q * 8 + j;
    int tap = k / CIN, ci = k % CIN;
    float v = 0.f;
    if (tap < 27) {
        if (w3 == nullptr) {
            v = w6[(n * CIN + ci) * 27 + tap];
        } else {
            if (n < 6) v = w6[(n * CIN + ci) * 27 + tap];
            else if (n < 9) v = w3[((n - 6) * CIN + ci) * 27 + tap];
        }
    }
    wB[i] = f2bf(v);
}

__global__ void k_bias9(const float* __restrict__ pb, const float* __restrict__ mb,
                        float* __restrict__ b9) {
    int i = threadIdx.x;
    if (i < 16) b9[i] = (i < 6) ? pb[i] : ((i < 9) ? mb[i - 6] : 0.f);
}

// ---------- Xray transposes (channels-last bf16) -----------------------------
__global__ __launch_bounds__(256) void k_xrayT(const float* __restrict__ X,
                                               unsigned short* __restrict__ XT) {
    int i = blockIdx.x * 256 + threadIdx.x;
    if (i >= 2 * XT_S) return;
    int b = i / XT_S, sp = i % XT_S;
    const float* src = X + (size_t)b * 16 * XT_S + sp;
    unsigned short* o = XT + (size_t)i * 16;
#pragma unroll
    for (int c = 0; c < 16; ++c) o[c] = f2bf(src[(size_t)c * XT_S]);
}

__global__ __launch_bounds__(256) void k_xpT(const float* __restrict__ X,
                                             unsigned short* __restrict__ XP) {
    int i = blockIdx.x * 256 + threadIdx.x;
    if (i >= 2 * XP_S) return;
    int b = i / XP_S, rc = i % XP_S;
    int r = rc / 130, c = rc % 130;
    unsigned short o[16];
    if (r >= 1 && r <= 128 && c >= 1 && c <= 128) {
        const float* src = X + (size_t)b * 16 * XT_S + (r - 1) * 128 + (c - 1);
#pragma unroll
        for (int ch = 0; ch < 16; ++ch) o[ch] = f2bf(src[(size_t)ch * XT_S]);
    } else {
#pragma unroll
        for (int ch = 0; ch < 16; ++ch) o[ch] = 0;
    }
    uint4* dst = (uint4*)(XP + (size_t)i * 16);
    uint4* s4 = (uint4*)o;
    dst[0] = s4[0]; dst[1] = s4[1];
}

// ---------- fill nin interior: ch0-15 = CT bf16, ch16-31 = xi ---------------
__global__ __launch_bounds__(256) void k_prep_nin(const float* __restrict__ CT,
                                                  const unsigned short* __restrict__ XT,
                                                  unsigned short* __restrict__ nin,
                                                  Geom g) {
    int vox = blockIdx.x * 256 + threadIdx.x;
    int b = blockIdx.y;
    int z = vox >> 12, x = (vox >> 6) & 63, y = vox & 63;
    unsigned short outv[32];
    const float* ct = CT + (size_t)b * 16 * DHW + vox;
#pragma unroll
    for (int c = 0; c < 16; ++c) outv[c] = f2bf(ct[(size_t)c * DHW]);
    float py, px;
    xray_coord(g, z, x, y, py, px);
    float fy = floorf(py), fx = floorf(px);
    int y0 = (int)fminf(fmaxf(fy, 0.f), 127.f);
    int y1 = (int)fminf(fmaxf(fy + 1.f, 0.f), 127.f);
    int x0 = (int)fminf(fmaxf(fx, 0.f), 127.f);
    int x1 = (int)fminf(fmaxf(fx + 1.f, 0.f), 127.f);
    float y0f = (float)y0, y1f = (float)y1, x0f = (float)x0, x1f = (float)x1;
    float glt = (1.f + (y0f - py)) * (1.f + (x0f - px));
    float grb = (1.f - (y1f - py)) * (1.f - (x1f - px));
    float grt = (1.f + (y0f - py)) * (1.f - (x1f - px));
    float glb = (1.f - (y1f - py)) * (1.f + (x0f - px));
    const unsigned short* base = XT + (size_t)b * XT_S * 16;
    const unsigned short* p00 = base + (size_t)(y0 * 128 + x0) * 16;
    const unsigned short* p11 = base + (size_t)(y1 * 128 + x1) * 16;
    const unsigned short* p01 = base + (size_t)(y0 * 128 + x1) * 16;
    const unsigned short* p10 = base + (size_t)(y1 * 128 + x0) * 16;
#pragma unroll
    for (int c = 0; c < 16; ++c) {
        float v = glt * bf2f(p00[c]) + grb * bf2f(p11[c]) +
                  grt * bf2f(p01[c]) + glb * bf2f(p10[c]);
        outv[16 + c] = f2bf(v);
    }
    size_t pp = (((size_t)(z + 1)) * PD + (x + 1)) * PD + (y + 1);
    uint4* dst = (uint4*)(nin + ((size_t)b * PS3 + pp) * 32);
    uint4* s4 = (uint4*)outv;
    dst[0] = s4[0]; dst[1] = s4[1]; dst[2] = s4[2]; dst[3] = s4[3];
}

// ---------- MFMA implicit-GEMM 3x3x3 conv ------------------------------------
// IN: padded NDHWC bf16 [B][PS3][CIN]. Block: 4z x 4x x 16y outputs, 4 waves.
// MODE 0: +bias -> offm fp32 [B][DHW][16]
// MODE 1: +bias, BN, leaky -> nh bf16 padded NDHWC [B][PS3][16]
// MODE 2: +bias -> out0 fp32 NCDHW
template <int CIN, int NK, int MODE>
__global__ __launch_bounds__(256) void k_conv_mfma(
    const unsigned short* __restrict__ IN, const unsigned short* __restrict__ wB,
    const float* __restrict__ bias,
    const float* __restrict__ bng, const float* __restrict__ bnb,
    const float* __restrict__ bnm, const float* __restrict__ bnv,
    float* __restrict__ outF, unsigned short* __restrict__ outH) {
    constexpr int NSLOT = CIN / 8;
    constexpr int SSH = (NSLOT == 4) ? 2 : 1;
    constexpr int NCHUNK = NSLOT * 648;  // 16B chunks
    __shared__ unsigned short lds[NSLOT * 648 * 8];

    int tid = threadIdx.x;
    int bid = blockIdx.x;
    int zt = bid & 15, xt = (bid >> 4) & 15, yt = bid >> 8;
    int b = blockIdx.y;

    // stage region [6z][6x][18y][CIN] -> LDS [slot][648 spatial][8ci]
    const unsigned short* gsrc = IN + (size_t)b * PS3 * CIN;
    for (int d = tid; d < NCHUNK; d += 256) {
        int slot = d & (NSLOT - 1);
        int sp = d >> SSH;
        int zz = sp / 108;
        int rem = sp - zz * 108;
        int xx = rem / 18, yy = rem - xx * 18;
        size_t gp = (((size_t)(zt * 4 + zz)) * PD + (xt * 4 + xx)) * PD + (yt * 16 + yy);
        uint4 v = *(const uint4*)(gsrc + gp * CIN + slot * 8);
        *(uint4*)&lds[(size_t)(slot * 648 + sp) * 8] = v;
    }

    // preload all weight fragments into registers
    int lane = tid & 63;
    short8 bw[NK];
    {
        const short8* wsrc = (const short8*)wB;
#pragma unroll
        for (int s = 0; s < NK; ++s) bw[s] = wsrc[s * 64 + lane];
    }
    int col = lane & 15, q = lane >> 4;
    float bcol = bias[col];
    float bsc = 1.f, bsh = 0.f;
    if (MODE == 1) {
        float sc = bng[col] * rsqrtf(bnv[col] + 1e-5f);
        bsc = sc;
        bsh = bnb[col] - bnm[col] * sc;
    }
    __syncthreads();

    int w = tid >> 6;  // wave id = vz
    for (int vx = 0; vx < 4; ++vx) {
        f32x4 acc = {0.f, 0.f, 0.f, 0.f};
#pragma unroll
        for (int s = 0; s < NK; ++s) {
            int tap = (s * 32 + q * 8) / CIN;
            if (CIN == 16) tap = min(tap, 26);  // K-pad: weights are zero there
            int slot = q & (NSLOT - 1);
            int dz = tap / 9;
            int trem = tap - dz * 9;
            int dx = trem / 3, dy = trem - dx * 3;
            int addr = ((slot * 648) + (w + dz) * 108 + (vx + dx) * 18 + col + dy) * 8;
            short8 a = *(const short8*)&lds[addr];
            acc = __builtin_amdgcn_mfma_f32_16x16x32_bf16(a, bw[s], acc, 0, 0, 0);
        }
        int z = zt * 4 + w, x = xt * 4 + vx;
        int yb = yt * 16 + q * 4;
        if (MODE == 0) {
            int vox = z * HW + x * 64 + yb;
            float* o = outF + ((size_t)b * DHW + vox) * 16 + col;
#pragma unroll
            for (int r = 0; r < 4; ++r) o[(size_t)r * 16] = acc[r] + bcol;
        } else if (MODE == 1) {
            size_t pp = (((size_t)(z + 1)) * PD + (x + 1)) * PD + (yb + 1);
            unsigned short* o = outH + ((size_t)b * PS3 + pp) * 16 + col;
#pragma unroll
            for (int r = 0; r < 4; ++r) {
                float v = acc[r] + bcol;
                v = v * bsc + bsh;
                v = (v >= 0.f) ? v : 0.2f * v;
                o[(size_t)r * 16] = f2bf(v);
            }
        } else {
            int vox = z * HW + x * 64 + yb;
            float* o = outF + ((size_t)b * 16 + col) * DHW + vox;
#pragma unroll
            for (int r = 0; r < 4; ++r) o[r] = acc[r] + bcol;
        }
    }
}

// ---------- deform: softmax + p_coor + bilerp_multi, writes nin ch16-31 ------
__global__ __launch_bounds__(256) void k_deform2(const float* __restrict__ offm,
                                                 const unsigned short* __restrict__ XP,
                                                 unsigned short* __restrict__ nin,
                                                 float* __restrict__ pcoor, Geom g) {
    int idx = blockIdx.x * 256 + threadIdx.x;
    int b = idx >> 18;
    int vox = idx & (DHW - 1);
    int z = vox >> 12, x = (vox >> 6) & 63, y = vox & 63;
    float bpy, bpx;
    xray_coord(g, z, x, y, bpy, bpx);
    const float* ob = offm + ((size_t)b * DHW + vox) * 16;
    float off[6];
#pragma unroll
    for (int k = 0; k < 6; ++k) off[k] = ob[k];
    float mv0 = ob[6], mv1 = ob[7], mv2 = ob[8];
    float mx = fmaxf(mv0, fmaxf(mv1, mv2));
    float e0 = __expf(mv0 - mx), e1 = __expf(mv1 - mx), e2 = __expf(mv2 - mx);
    float inv = 1.f / (e0 + e1 + e2);
    float ms[3] = {e0 * inv, e1 * inv, e2 * inv};

    float pys[3], pxs[3];
#pragma unroll
    for (int p = 0; p < 3; ++p) {
        pys[p] = fminf(fmaxf(off[p] + bpy + 1.f, 0.f), 129.f);
        pxs[p] = fminf(fmaxf(off[3 + p] + bpx + 1.f, 0.f), 129.f);
    }
    float* pc = pcoor + (size_t)idx * 6;
    pc[0] = pys[0]; pc[1] = pys[1]; pc[2] = pys[2];
    pc[3] = pxs[0]; pc[4] = pxs[1]; pc[5] = pxs[2];

    float acc[16];
#pragma unroll
    for (int c = 0; c < 16; ++c) acc[c] = 0.f;
    const unsigned short* xpb = XP + (size_t)b * XP_S * 16;
#pragma unroll
    for (int p = 0; p < 3; ++p) {
        float py = pys[p], px = pxs[p];
        float fy = floorf(py), fx = floorf(px);
        int y0 = (int)fminf(fmaxf(fy, 0.f), 129.f);
        int y1 = (int)fminf(fmaxf(fy + 1.f, 0.f), 129.f);
        int x0 = (int)fminf(fmaxf(fx, 0.f), 129.f);
        int x1 = (int)fminf(fmaxf(fx + 1.f, 0.f), 129.f);
        float y0f = (float)y0, y1f = (float)y1, x0f = (float)x0, x1f = (float)x1;
        float glt = (1.f + (y0f - py)) * (1.f + (x0f - px));
        float grb = (1.f - (y1f - py)) * (1.f - (x1f - px));
        float grt = (1.f + (y0f - py)) * (1.f - (x1f - px));
        float glb = (1.f - (y1f - py)) * (1.f + (x0f - px));
        const unsigned short* p00 = xpb + (size_t)(y0 * 130 + x0) * 16;
        const unsigned short* p11 = xpb + (size_t)(y1 * 130 + x1) * 16;
        const unsigned short* p01 = xpb + (size_t)(y0 * 130 + x1) * 16;
        const unsigned short* p10 = xpb + (size_t)(y1 * 130 + x0) * 16;
        float mp = ms[p];
#pragma unroll
        for (int c = 0; c < 16; ++c) {
            float v = glt * bf2f(p00[c]) + grb * bf2f(p11[c]) +
                      grt * bf2f(p01[c]) + glb * bf2f(p10[c]);
            acc[c] += mp * v;
        }
    }
    size_t pp = (((size_t)(z + 1)) * PD + (x + 1)) * PD + (y + 1);
    unsigned short outv[16];
#pragma unroll
    for (int c = 0; c < 16; ++c) outv[c] = f2bf(acc[c]);
    uint4* dst = (uint4*)(nin + ((size_t)b * PS3 + pp) * 32 + 16);
    uint4* s4 = (uint4*)outv;
    dst[0] = s4[0]; dst[1] = s4[1];
}

static void compute_geom(Geom& g) {
    const double sdr = 200.0, del = 2.0;
    double theta = M_PI, phi = 0.0, gam = M_PI / 2;
    double Rz[3][3] = {{cos(theta), -sin(theta), 0}, {sin(theta), cos(theta), 0}, {0, 0, 1}};
    double Ry[3][3] = {{cos(phi), 0, sin(phi)}, {0, 1, 0}, {-sin(phi), 0, cos(phi)}};
    double Rx[3][3] = {{1, 0, 0}, {0, cos(gam), -sin(gam)}, {0, sin(gam), cos(gam)}};
    double M[3][3], R[3][3];
    for (int i = 0; i < 3; i++)
        for (int j = 0; j < 3; j++) {
            double s = 0;
            for (int k = 0; k < 3; k++) s += Rz[i][k] * Ry[k][j];
            M[i][j] = s;
        }
    for (int i = 0; i < 3; i++)
        for (int j = 0; j < 3; j++) {
            double s = 0;
            for (int k = 0; k < 3; k++) s += M[i][k] * Rx[k][j];
            R[i][j] = sdr * s;
        }
    double trans[3] = {32.0, 32.0, 32.0};
    double src[3], ctr[3];
    for (int k = 0; k < 3; k++) {
        src[k] = R[k][0] + trans[k];
        ctr[k] = -R[k][0] + trans[k];
    }
    double Rn[3][3];
    for (int i = 0; i < 3; i++) {
        double n = sqrt(R[i][0] * R[i][0] + R[i][1] * R[i][1] + R[i][2] * R[i][2]);
        for (int j = 0; j < 3; j++) Rn[i][j] = R[i][j] / n;
    }
    double u[3], v[3];
    for (int k = 0; k < 3; k++) { u[k] = Rn[k][1]; v[k] = Rn[k][2]; }
    double tmin[3], tmax[3];
    for (int k = 0; k < 3; k++) {
        double a = 127.0 * fabs(u[k]) + 127.0 * fabs(v[k]);
        tmin[k] = ctr[k] - a;
        tmax[k] = ctr[k] + a;
    }
    double delta[3];
    for (int k = 0; k < 3; k++) delta[k] = del * u[k] + del * v[k];
    g.s0 = src[0]; g.s1 = src[1]; g.s2 = src[2];
    g.c0ms0 = ctr[0] - src[0];
    g.tmin1 = tmin[1]; g.tmax1 = tmax[1];
    g.tmin2 = tmin[2]; g.tmax2 = tmax[2];
    g.d1 = delta[1]; g.d2 = delta[2];
}

// workspace layout (bytes)
constexpr size_t NIN_B  = (size_t)2 * PS3 * 32 * 2;       // 36,799,488
constexpr size_t NH_B   = (size_t)2 * PS3 * 16 * 2;       // 18,399,744
constexpr size_t OFFM_B = (size_t)2 * DHW * 16 * 4;       // 33,554,432
constexpr size_t XT_B   = (size_t)2 * XT_S * 16 * 2;      // 1,048,576
constexpr size_t XP_B   = (size_t)2 * XP_S * 16 * 2;      // 1,081,600
constexpr size_t WB9_B  = (size_t)27 * 64 * 8 * 2;        // 27,648
constexpr size_t WB1_B  = WB9_B;
constexpr size_t WB2_B  = (size_t)14 * 64 * 8 * 2;        // 14,336

constexpr size_t O_NIN  = 0;
constexpr size_t O_NH   = O_NIN + NIN_B;
constexpr size_t O_OFFM = O_NH + NH_B;
constexpr size_t O_XT   = O_OFFM + OFFM_B;
constexpr size_t O_XP   = O_XT + XT_B;
constexpr size_t O_WB9  = O_XP + XP_B;
constexpr size_t O_WB1  = O_WB9 + WB9_B;
constexpr size_t O_WB2  = O_WB1 + WB1_B;
constexpr size_t O_B9   = O_WB2 + WB2_B;

extern "C" void kernel_launch(void* const* d_in, const int* in_sizes, int n_in,
                              void* d_out, int out_size, void* d_ws, size_t ws_size,
                              hipStream_t stream) {
    (void)in_sizes; (void)n_in; (void)out_size; (void)ws_size;
    const float* CT = (const float*)d_in[0];
    const float* Xray = (const float*)d_in[1];
    const float* pW = (const float*)d_in[2];
    const float* pb = (const float*)d_in[3];
    const float* mW = (const float*)d_in[4];
    const float* mb = (const float*)d_in[5];
    const float* w1 = (const float*)d_in[6];
    const float* b1 = (const float*)d_in[7];
    const float* w2 = (const float*)d_in[8];
    const float* b2 = (const float*)d_in[9];
    const float* bng = (const float*)d_in[10];
    const float* bnb = (const float*)d_in[11];
    const float* bnm = (const float*)d_in[12];
    const float* bnv = (const float*)d_in[13];

    char* ws = (char*)d_ws;
    unsigned short* nin = (unsigned short*)(ws + O_NIN);
    unsigned short* nh  = (unsigned short*)(ws + O_NH);
    float* offm = (float*)(ws + O_OFFM);
    unsigned short* XT = (unsigned short*)(ws + O_XT);
    unsigned short* XP = (unsigned short*)(ws + O_XP);
    unsigned short* wB9 = (unsigned short*)(ws + O_WB9);
    unsigned short* wB1 = (unsigned short*)(ws + O_WB1);
    unsigned short* wB2 = (unsigned short*)(ws + O_WB2);
    float* b9 = (float*)(ws + O_B9);

    float* out0 = (float*)d_out;             // (2,16,64,64,64)
    float* out1 = out0 + (size_t)32 * DHW;   // (2,64,64,64,6)

    Geom g;
    compute_geom(g);

    // zero padded input buffers (halo must be 0 every call)
    hipMemsetAsync(nin, 0, NIN_B, stream);
    hipMemsetAsync(nh, 0, NH_B, stream);

    // weight/bias prep
    k_wprep<32, 27><<<54, 256, 0, stream>>>(pW, mW, wB9);
    k_wprep<32, 27><<<54, 256, 0, stream>>>(w1, nullptr, wB1);
    k_wprep<16, 14><<<28, 256, 0, stream>>>(w2, nullptr, wB2);
    k_bias9<<<1, 64, 0, stream>>>(pb, mb, b9);

    // xray channels-last transposes
    k_xrayT<<<(2 * XT_S + 255) / 256, 256, 0, stream>>>(Xray, XT);
    k_xpT<<<(2 * XP_S + 255) / 256, 256, 0, stream>>>(Xray, XP);

    // nin interior: CT + xi
    k_prep_nin<<<dim3(DHW / 256, 2), 256, 0, stream>>>(CT, XT, nin, g);

    // conv9 (32 -> 9, padded to 16) -> offm channels-last fp32
    k_conv_mfma<32, 27, 0><<<dim3(1024, 2), 256, 0, stream>>>(
        nin, wB9, b9, nullptr, nullptr, nullptr, nullptr, offm, nullptr);

    // deform: softmax + p_coor + gather; writes Xsum into nin ch16-31
    k_deform2<<<(2 * DHW) / 256, 256, 0, stream>>>(offm, XP, nin, out1, g);

    // conv1 (32 -> 16) + BN + leaky -> nh (padded bf16)
    k_conv_mfma<32, 27, 1><<<dim3(1024, 2), 256, 0, stream>>>(
        nin, wB1, b1, bng, bnb, bnm, bnv, nullptr, nh);

    // conv2 (16 -> 16) -> out0 (NCDHW fp32)
    k_conv_mfma<16, 14, 2><<<dim3(1024, 2), 256, 0, stream>>>(
        nh, wB2, b2, nullptr, nullptr, nullptr, nullptr, out0, nullptr);
}

// Round 10
// 225.071 us; speedup vs baseline: 4.7302x; 1.0961x over previous
//
#include <hip/hip_runtime.h>
#include <hip/hip_bf16.h>
#include <math.h>

// Problem constants
constexpr int Dd = 64, Hh = 64, Ww = 64;
constexpr int DHW = Dd * Hh * Ww;   // 262144
constexpr int HW = Hh * Ww;         // 4096
constexpr int XT_S = 128 * 128;     // XrayT spatial
constexpr int XP_S = 130 * 130;     // padded xray spatial

using short8 = __attribute__((ext_vector_type(8))) short;
using f32x4  = __attribute__((ext_vector_type(4))) float;

struct Geom {
    double s0, s1, s2;
    double c0ms0;
    double tmin1, tmax1, tmin2, tmax2;
    double d1, d2;
};

__device__ __forceinline__ void xray_coord(const Geom g, int z, int x, int y,
                                           float& py, float& px) {
    double wgt = g.c0ms0 / ((double)z - g.s0);
    double X1 = wgt * ((double)x - g.s1) + g.s1;
    X1 = fmin(fmax(X1, g.tmin1), g.tmax1);
    double X2 = wgt * ((double)y - g.s2) + g.s2;
    X2 = fmin(fmax(X2, g.tmin2), g.tmax2);
    py = (float)((X1 - g.tmin1) / g.d1);
    px = (float)((X2 - g.tmin2) / g.d2);
}

__device__ __forceinline__ float bf2f(unsigned short u) {
    union { unsigned int i; float f; } v;
    v.i = ((unsigned int)u) << 16;
    return v.f;
}
__device__ __forceinline__ unsigned short f2bf(float f) {
    __hip_bfloat16 h = __float2bfloat16(f);
    return *reinterpret_cast<unsigned short*>(&h);
}

// ---------- weight prep: wB[s][lane][j] bf16 in MFMA B-frag order ------------
template <int CIN, int NK>
__global__ __launch_bounds__(256) void k_wprep(const float* __restrict__ w6,
                                               const float* __restrict__ w3,
                                               unsigned short* __restrict__ wB) {
    int i = blockIdx.x * 256 + threadIdx.x;
    if (i >= NK * 64 * 8) return;
    int s = i >> 9, l = (i >> 3) & 63, j = i & 7;
    int n = l & 15, q = l >> 4;
    int k = s * 32 + q * 8 + j;
    int tap = k / CIN, ci = k % CIN;
    float v = 0.f;
    if (tap < 27) {
        if (w3 == nullptr) {
            v = w6[(n * CIN + ci) * 27 + tap];
        } else {
            if (n < 6) v = w6[(n * CIN + ci) * 27 + tap];
            else if (n < 9) v = w3[((n - 6) * CIN + ci) * 27 + tap];
        }
    }
    wB[i] = f2bf(v);
}

__global__ void k_bias9(const float* __restrict__ pb, const float* __restrict__ mb,
                        float* __restrict__ b9) {
    int i = threadIdx.x;
    if (i < 16) b9[i] = (i < 6) ? pb[i] : ((i < 9) ? mb[i - 6] : 0.f);
}

// ---------- Xray transposes (channels-last bf16) -----------------------------
__global__ __launch_bounds__(256) void k_xrayT(const float* __restrict__ X,
                                               unsigned short* __restrict__ XT) {
    int i = blockIdx.x * 256 + threadIdx.x;
    if (i >= 2 * XT_S) return;
    int b = i / XT_S, sp = i % XT_S;
    const float* src = X + (size_t)b * 16 * XT_S + sp;
    unsigned short* o = XT + (size_t)i * 16;
#pragma unroll
    for (int c = 0; c < 16; ++c) o[c] = f2bf(src[(size_t)c * XT_S]);
}

__global__ __launch_bounds__(256) void k_xpT(const float* __restrict__ X,
                                             unsigned short* __restrict__ XP) {
    int i = blockIdx.x * 256 + threadIdx.x;
    if (i >= 2 * XP_S) return;
    int b = i / XP_S, rc = i % XP_S;
    int r = rc / 130, c = rc % 130;
    unsigned short o[16];
    if (r >= 1 && r <= 128 && c >= 1 && c <= 128) {
        const float* src = X + (size_t)b * 16 * XT_S + (r - 1) * 128 + (c - 1);
#pragma unroll
        for (int ch = 0; ch < 16; ++ch) o[ch] = f2bf(src[(size_t)ch * XT_S]);
    } else {
#pragma unroll
        for (int ch = 0; ch < 16; ++ch) o[ch] = 0;
    }
    uint4* dst = (uint4*)(XP + (size_t)i * 16);
    uint4* s4 = (uint4*)o;
    dst[0] = s4[0]; dst[1] = s4[1];
}

// ---------- fill nin (unpadded [B][DHW][32]): ch0-15 = CT, ch16-31 = xi ------
__global__ __launch_bounds__(256) void k_prep_nin(const float* __restrict__ CT,
                                                  const unsigned short* __restrict__ XT,
                                                  unsigned short* __restrict__ nin,
                                                  Geom g) {
    int vox = blockIdx.x * 256 + threadIdx.x;
    int b = blockIdx.y;
    int z = vox >> 12, x = (vox >> 6) & 63, y = vox & 63;
    unsigned short outv[32];
    const float* ct = CT + (size_t)b * 16 * DHW + vox;
#pragma unroll
    for (int c = 0; c < 16; ++c) outv[c] = f2bf(ct[(size_t)c * DHW]);
    float py, px;
    xray_coord(g, z, x, y, py, px);
    float fy = floorf(py), fx = floorf(px);
    int y0 = (int)fminf(fmaxf(fy, 0.f), 127.f);
    int y1 = (int)fminf(fmaxf(fy + 1.f, 0.f), 127.f);
    int x0 = (int)fminf(fmaxf(fx, 0.f), 127.f);
    int x1 = (int)fminf(fmaxf(fx + 1.f, 0.f), 127.f);
    float y0f = (float)y0, y1f = (float)y1, x0f = (float)x0, x1f = (float)x1;
    float glt = (1.f + (y0f - py)) * (1.f + (x0f - px));
    float grb = (1.f - (y1f - py)) * (1.f - (x1f - px));
    float grt = (1.f + (y0f - py)) * (1.f - (x1f - px));
    float glb = (1.f - (y1f - py)) * (1.f + (x0f - px));
    const unsigned short* base = XT + (size_t)b * XT_S * 16;
    const unsigned short* p00 = base + (size_t)(y0 * 128 + x0) * 16;
    const unsigned short* p11 = base + (size_t)(y1 * 128 + x1) * 16;
    const unsigned short* p01 = base + (size_t)(y0 * 128 + x1) * 16;
    const unsigned short* p10 = base + (size_t)(y1 * 128 + x0) * 16;
#pragma unroll
    for (int c = 0; c < 16; ++c) {
        float v = glt * bf2f(p00[c]) + grb * bf2f(p11[c]) +
                  grt * bf2f(p01[c]) + glb * bf2f(p10[c]);
        outv[16 + c] = f2bf(v);
    }
    uint4* dst = (uint4*)(nin + ((size_t)b * DHW + vox) * 32);
    uint4* s4 = (uint4*)outv;
    dst[0] = s4[0]; dst[1] = s4[1]; dst[2] = s4[2]; dst[3] = s4[3];
}

// ---------- fused conv9 (32->16 MFMA) + softmax + p_coor + deform gather -----
// Block: 4z x 4x x 16y outputs. Writes xs (bf16 [B][DHW][16]) + pcoor.
__global__ __launch_bounds__(256) void k_conv9_deform(
    const unsigned short* __restrict__ IN, const unsigned short* __restrict__ wB,
    const float* __restrict__ bias, const unsigned short* __restrict__ XP,
    unsigned short* __restrict__ xs, float* __restrict__ pcoor, Geom g) {
    __shared__ char smem[4 * 648 * 8 * 2];   // 41472 B: staging, then ptile alias
    unsigned short* lds = (unsigned short*)smem;
    float* ptile = (float*)smem;             // [256][17]

    int tid = threadIdx.x;
    int bid = blockIdx.x;
    int zt = bid & 15, xt = (bid >> 4) & 15, yt = bid >> 8;
    int b = blockIdx.y;

    // stage 6x6x18 region x 32ch, bounds-checked (zero outside volume)
    const unsigned short* gsrc = IN + (size_t)b * DHW * 32;
    for (int d = tid; d < 4 * 648; d += 256) {
        int slot = d & 3;
        int sp = d >> 2;
        int zz = sp / 108;
        int rem = sp - zz * 108;
        int xx = rem / 18, yy = rem - xx * 18;
        int gz = zt * 4 + zz - 1, gx = xt * 4 + xx - 1, gy = yt * 16 + yy - 1;
        uint4 v = {0u, 0u, 0u, 0u};
        if ((unsigned)gz < 64u && (unsigned)gx < 64u && (unsigned)gy < 64u) {
            size_t gp = (size_t)gz * HW + gx * 64 + gy;
            v = *(const uint4*)(gsrc + gp * 32 + slot * 8);
        }
        *(uint4*)&lds[(size_t)(slot * 648 + sp) * 8] = v;
    }

    int lane = tid & 63;
    short8 bw[27];
    {
        const short8* wsrc = (const short8*)wB;
#pragma unroll
        for (int s = 0; s < 27; ++s) bw[s] = wsrc[s * 64 + lane];
    }
    int col = lane & 15, q = lane >> 4;
    float bcol = bias[col];
    __syncthreads();

    int w = tid >> 6;
    float accs[4][4];
    for (int vx = 0; vx < 4; ++vx) {
        f32x4 acc = {0.f, 0.f, 0.f, 0.f};
#pragma unroll
        for (int s = 0; s < 27; ++s) {
            int tap = s;
            int slot = q & 3;
            int dz = tap / 9;
            int trem = tap - dz * 9;
            int dx = trem / 3, dy = trem - dx * 3;
            int addr = ((slot * 648) + (w + dz) * 108 + (vx + dx) * 18 + col + dy) * 8;
            short8 a = *(const short8*)&lds[addr];
            acc = __builtin_amdgcn_mfma_f32_16x16x32_bf16(a, bw[s], acc, 0, 0, 0);
        }
#pragma unroll
        for (int r = 0; r < 4; ++r) accs[vx][r] = acc[r] + bcol;
    }
    __syncthreads();  // all MFMA LDS reads done; safe to overwrite with ptile
#pragma unroll
    for (int vx = 0; vx < 4; ++vx)
#pragma unroll
        for (int r = 0; r < 4; ++r)
            ptile[(w * 64 + vx * 16 + q * 4 + r) * 17 + col] = accs[vx][r];
    __syncthreads();

    // per-thread deform for voxel local = tid
    int z = zt * 4 + (tid >> 6);
    int x = xt * 4 + ((tid >> 4) & 3);
    int y = yt * 16 + (tid & 15);
    int vox = z * HW + x * 64 + y;
    const float* pt = &ptile[tid * 17];
    float bpy, bpx;
    xray_coord(g, z, x, y, bpy, bpx);
    float off0 = pt[0], off1 = pt[1], off2 = pt[2];
    float off3 = pt[3], off4 = pt[4], off5 = pt[5];
    float mv0 = pt[6], mv1 = pt[7], mv2 = pt[8];
    float mx = fmaxf(mv0, fmaxf(mv1, mv2));
    float e0 = __expf(mv0 - mx), e1 = __expf(mv1 - mx), e2 = __expf(mv2 - mx);
    float inv = 1.f / (e0 + e1 + e2);
    float ms[3] = {e0 * inv, e1 * inv, e2 * inv};

    float pys[3], pxs3[3];
    pys[0] = fminf(fmaxf(off0 + bpy + 1.f, 0.f), 129.f);
    pys[1] = fminf(fmaxf(off1 + bpy + 1.f, 0.f), 129.f);
    pys[2] = fminf(fmaxf(off2 + bpy + 1.f, 0.f), 129.f);
    pxs3[0] = fminf(fmaxf(off3 + bpx + 1.f, 0.f), 129.f);
    pxs3[1] = fminf(fmaxf(off4 + bpx + 1.f, 0.f), 129.f);
    pxs3[2] = fminf(fmaxf(off5 + bpx + 1.f, 0.f), 129.f);
    float* pc = pcoor + ((size_t)b * DHW + vox) * 6;
    pc[0] = pys[0]; pc[1] = pys[1]; pc[2] = pys[2];
    pc[3] = pxs3[0]; pc[4] = pxs3[1]; pc[5] = pxs3[2];

    float acc16[16];
#pragma unroll
    for (int c = 0; c < 16; ++c) acc16[c] = 0.f;
    const unsigned short* xpb = XP + (size_t)b * XP_S * 16;
#pragma unroll
    for (int p = 0; p < 3; ++p) {
        float py = pys[p], px = pxs3[p];
        float fy = floorf(py), fx = floorf(px);
        int y0 = (int)fminf(fmaxf(fy, 0.f), 129.f);
        int y1 = (int)fminf(fmaxf(fy + 1.f, 0.f), 129.f);
        int x0 = (int)fminf(fmaxf(fx, 0.f), 129.f);
        int x1 = (int)fminf(fmaxf(fx + 1.f, 0.f), 129.f);
        float y0f = (float)y0, y1f = (float)y1, x0f = (float)x0, x1f = (float)x1;
        float glt = (1.f + (y0f - py)) * (1.f + (x0f - px));
        float grb = (1.f - (y1f - py)) * (1.f - (x1f - px));
        float grt = (1.f + (y0f - py)) * (1.f - (x1f - px));
        float glb = (1.f - (y1f - py)) * (1.f + (x0f - px));
        const unsigned short* p00 = xpb + (size_t)(y0 * 130 + x0) * 16;
        const unsigned short* p11 = xpb + (size_t)(y1 * 130 + x1) * 16;
        const unsigned short* p01 = xpb + (size_t)(y0 * 130 + x1) * 16;
        const unsigned short* p10 = xpb + (size_t)(y1 * 130 + x0) * 16;
        float mp = ms[p];
#pragma unroll
        for (int c = 0; c < 16; ++c) {
            float v = glt * bf2f(p00[c]) + grb * bf2f(p11[c]) +
                      grt * bf2f(p01[c]) + glb * bf2f(p10[c]);
            acc16[c] += mp * v;
        }
    }
    unsigned short outv[16];
#pragma unroll
    for (int c = 0; c < 16; ++c) outv[c] = f2bf(acc16[c]);
    uint4* dst = (uint4*)(xs + ((size_t)b * DHW + vox) * 16);
    uint4* s4 = (uint4*)outv;
    dst[0] = s4[0]; dst[1] = s4[1];
}

// ---------- MFMA implicit-GEMM conv (unpadded, bounds-checked staging) -------
// MODE 1: CIN=32 dual-src (nin ch0-15 + xs), +bias, BN, leaky -> nh bf16 [B][DHW][16]
// MODE 2: CIN=16 single-src nh, +bias -> out0 fp32 NCDHW
template <int CIN, int NK, int MODE>
__global__ __launch_bounds__(256) void k_conv_mfma(
    const unsigned short* __restrict__ IN, const unsigned short* __restrict__ IN2,
    const unsigned short* __restrict__ wB, const float* __restrict__ bias,
    const float* __restrict__ bng, const float* __restrict__ bnb,
    const float* __restrict__ bnm, const float* __restrict__ bnv,
    float* __restrict__ outF, unsigned short* __restrict__ outH) {
    constexpr int NSLOT = CIN / 8;
    constexpr int SSH = (NSLOT == 4) ? 2 : 1;
    constexpr int NCHUNK = NSLOT * 648;
    __shared__ unsigned short lds[NSLOT * 648 * 8];

    int tid = threadIdx.x;
    int bid = blockIdx.x;
    int zt = bid & 15, xt = (bid >> 4) & 15, yt = bid >> 8;
    int b = blockIdx.y;

    const unsigned short* src1 = IN + (size_t)b * DHW * ((MODE == 1) ? 32 : 16);
    const unsigned short* src2 =
        (MODE == 1) ? (IN2 + (size_t)b * DHW * 16) : nullptr;
    for (int d = tid; d < NCHUNK; d += 256) {
        int slot = d & (NSLOT - 1);
        int sp = d >> SSH;
        int zz = sp / 108;
        int rem = sp - zz * 108;
        int xx = rem / 18, yy = rem - xx * 18;
        int gz = zt * 4 + zz - 1, gx = xt * 4 + xx - 1, gy = yt * 16 + yy - 1;
        uint4 v = {0u, 0u, 0u, 0u};
        if ((unsigned)gz < 64u && (unsigned)gx < 64u && (unsigned)gy < 64u) {
            size_t gp = (size_t)gz * HW + gx * 64 + gy;
            if (MODE == 1) {
                if (slot < 2) v = *(const uint4*)(src1 + gp * 32 + slot * 8);
                else v = *(const uint4*)(src2 + gp * 16 + (slot - 2) * 8);
            } else {
                v = *(const uint4*)(src1 + gp * 16 + slot * 8);
            }
        }
        *(uint4*)&lds[(size_t)(slot * 648 + sp) * 8] = v;
    }

    int lane = tid & 63;
    short8 bw[NK];
    {
        const short8* wsrc = (const short8*)wB;
#pragma unroll
        for (int s = 0; s < NK; ++s) bw[s] = wsrc[s * 64 + lane];
    }
    int col = lane & 15, q = lane >> 4;
    float bcol = bias[col];
    float bsc = 1.f, bsh = 0.f;
    if (MODE == 1) {
        float sc = bng[col] * rsqrtf(bnv[col] + 1e-5f);
        bsc = sc;
        bsh = bnb[col] - bnm[col] * sc;
    }
    __syncthreads();

    int w = tid >> 6;
    for (int vx = 0; vx < 4; ++vx) {
        f32x4 acc = {0.f, 0.f, 0.f, 0.f};
#pragma unroll
        for (int s = 0; s < NK; ++s) {
            int tap = (s * 32 + q * 8) / CIN;
            if (CIN == 16) tap = min(tap, 26);  // K-pad: weights zero there
            int slot = q & (NSLOT - 1);
            int dz = tap / 9;
            int trem = tap - dz * 9;
            int dx = trem / 3, dy = trem - dx * 3;
            int addr = ((slot * 648) + (w + dz) * 108 + (vx + dx) * 18 + col + dy) * 8;
            short8 a = *(const short8*)&lds[addr];
            acc = __builtin_amdgcn_mfma_f32_16x16x32_bf16(a, bw[s], acc, 0, 0, 0);
        }
        int z = zt * 4 + w, x = xt * 4 + vx;
        int yb = yt * 16 + q * 4;
        int vox = z * HW + x * 64 + yb;
        if (MODE == 1) {
            unsigned short* o = outH + ((size_t)b * DHW + vox) * 16 + col;
#pragma unroll
            for (int r = 0; r < 4; ++r) {
                float v = acc[r] + bcol;
                v = v * bsc + bsh;
                v = (v >= 0.f) ? v : 0.2f * v;
                o[(size_t)r * 16] = f2bf(v);
            }
        } else {
            float* o = outF + ((size_t)b * 16 + col) * DHW + vox;
#pragma unroll
            for (int r = 0; r < 4; ++r) o[r] = acc[r] + bcol;
        }
    }
}

static void compute_geom(Geom& g) {
    const double sdr = 200.0, del = 2.0;
    double theta = M_PI, phi = 0.0, gam = M_PI / 2;
    double Rz[3][3] = {{cos(theta), -sin(theta), 0}, {sin(theta), cos(theta), 0}, {0, 0, 1}};
    double Ry[3][3] = {{cos(phi), 0, sin(phi)}, {0, 1, 0}, {-sin(phi), 0, cos(phi)}};
    double Rx[3][3] = {{1, 0, 0}, {0, cos(gam), -sin(gam)}, {0, sin(gam), cos(gam)}};
    double M[3][3], R[3][3];
    for (int i = 0; i < 3; i++)
        for (int j = 0; j < 3; j++) {
            double s = 0;
            for (int k = 0; k < 3; k++) s += Rz[i][k] * Ry[k][j];
            M[i][j] = s;
        }
    for (int i = 0; i < 3; i++)
        for (int j = 0; j < 3; j++) {
            double s = 0;
            for (int k = 0; k < 3; k++) s += M[i][k] * Rx[k][j];
            R[i][j] = sdr * s;
        }
    double trans[3] = {32.0, 32.0, 32.0};
    double src[3], ctr[3];
    for (int k = 0; k < 3; k++) {
        src[k] = R[k][0] + trans[k];
        ctr[k] = -R[k][0] + trans[k];
    }
    double Rn[3][3];
    for (int i = 0; i < 3; i++) {
        double n = sqrt(R[i][0] * R[i][0] + R[i][1] * R[i][1] + R[i][2] * R[i][2]);
        for (int j = 0; j < 3; j++) Rn[i][j] = R[i][j] / n;
    }
    double u[3], v[3];
    for (int k = 0; k < 3; k++) { u[k] = Rn[k][1]; v[k] = Rn[k][2]; }
    double tmin[3], tmax[3];
    for (int k = 0; k < 3; k++) {
        double a = 127.0 * fabs(u[k]) + 127.0 * fabs(v[k]);
        tmin[k] = ctr[k] - a;
        tmax[k] = ctr[k] + a;
    }
    double delta[3];
    for (int k = 0; k < 3; k++) delta[k] = del * u[k] + del * v[k];
    g.s0 = src[0]; g.s1 = src[1]; g.s2 = src[2];
    g.c0ms0 = ctr[0] - src[0];
    g.tmin1 = tmin[1]; g.tmax1 = tmax[1];
    g.tmin2 = tmin[2]; g.tmax2 = tmax[2];
    g.d1 = delta[1]; g.d2 = delta[2];
}

// workspace layout (bytes)
constexpr size_t NIN_B = (size_t)2 * DHW * 32 * 2;   // 33,554,432
constexpr size_t XS_B  = (size_t)2 * DHW * 16 * 2;   // 16,777,216
constexpr size_t NH_B  = XS_B;                       // 16,777,216
constexpr size_t XT_B  = (size_t)2 * XT_S * 16 * 2;  // 1,048,576
constexpr size_t XP_B  = (size_t)2 * XP_S * 16 * 2;  // 1,081,600
constexpr size_t WB9_B = (size_t)27 * 64 * 8 * 2;    // 27,648
constexpr size_t WB1_B = WB9_B;
constexpr size_t WB2_B = (size_t)14 * 64 * 8 * 2;    // 14,336

constexpr size_t O_NIN = 0;
constexpr size_t O_XS  = O_NIN + NIN_B;
constexpr size_t O_NH  = O_XS + XS_B;
constexpr size_t O_XT  = O_NH + NH_B;
constexpr size_t O_XP  = O_XT + XT_B;
constexpr size_t O_WB9 = O_XP + XP_B;
constexpr size_t O_WB1 = O_WB9 + WB9_B;
constexpr size_t O_WB2 = O_WB1 + WB1_B;
constexpr size_t O_B9  = O_WB2 + WB2_B;

extern "C" void kernel_launch(void* const* d_in, const int* in_sizes, int n_in,
                              void* d_out, int out_size, void* d_ws, size_t ws_size,
                              hipStream_t stream) {
    (void)in_sizes; (void)n_in; (void)out_size; (void)ws_size;
    const float* CT = (const float*)d_in[0];
    const float* Xray = (const float*)d_in[1];
    const float* pW = (const float*)d_in[2];
    const float* pb = (const float*)d_in[3];
    const float* mW = (const float*)d_in[4];
    const float* mb = (const float*)d_in[5];
    const float* w1 = (const float*)d_in[6];
    const float* b1 = (const float*)d_in[7];
    const float* w2 = (const float*)d_in[8];
    const float* b2 = (const float*)d_in[9];
    const float* bng = (const float*)d_in[10];
    const float* bnb = (const float*)d_in[11];
    const float* bnm = (const float*)d_in[12];
    const float* bnv = (const float*)d_in[13];

    char* ws = (char*)d_ws;
    unsigned short* nin = (unsigned short*)(ws + O_NIN);
    unsigned short* xs  = (unsigned short*)(ws + O_XS);
    unsigned short* nh  = (unsigned short*)(ws + O_NH);
    unsigned short* XT  = (unsigned short*)(ws + O_XT);
    unsigned short* XP  = (unsigned short*)(ws + O_XP);
    unsigned short* wB9 = (unsigned short*)(ws + O_WB9);
    unsigned short* wB1 = (unsigned short*)(ws + O_WB1);
    unsigned short* wB2 = (unsigned short*)(ws + O_WB2);
    float* b9 = (float*)(ws + O_B9);

    float* out0 = (float*)d_out;             // (2,16,64,64,64)
    float* out1 = out0 + (size_t)32 * DHW;   // (2,64,64,64,6)

    Geom g;
    compute_geom(g);

    // weight/bias prep
    k_wprep<32, 27><<<54, 256, 0, stream>>>(pW, mW, wB9);
    k_wprep<32, 27><<<54, 256, 0, stream>>>(w1, nullptr, wB1);
    k_wprep<16, 14><<<28, 256, 0, stream>>>(w2, nullptr, wB2);
    k_bias9<<<1, 64, 0, stream>>>(pb, mb, b9);

    // xray channels-last transposes
    k_xrayT<<<(2 * XT_S + 255) / 256, 256, 0, stream>>>(Xray, XT);
    k_xpT<<<(2 * XP_S + 255) / 256, 256, 0, stream>>>(Xray, XP);

    // nin: CT + xi (unpadded NDHWC)
    k_prep_nin<<<dim3(DHW / 256, 2), 256, 0, stream>>>(CT, XT, nin, g);

    // fused conv9 + softmax + p_coor + deform gather -> xs, out1
    k_conv9_deform<<<dim3(1024, 2), 256, 0, stream>>>(nin, wB9, b9, XP, xs, out1, g);

    // conv1 (nin ch0-15 + xs -> 16) + BN + leaky -> nh
    k_conv_mfma<32, 27, 1><<<dim3(1024, 2), 256, 0, stream>>>(
        nin, xs, wB1, b1, bng, bnb, bnm, bnv, nullptr, nh);

    // conv2 (16 -> 16) -> out0 (NCDHW fp32)
    k_conv_mfma<16, 14, 2><<<dim3(1024, 2), 256, 0, stream>>>(
        nh, nullptr, wB2, b2, nullptr, nullptr, nullptr, nullptr, out0, nullptr);
}